// Round 5
// baseline (419.120 us; speedup 1.0000x reference)
//
#include <hip/hip_runtime.h>

#define SEQ_LEN   100
#define IN_DIM    32
#define EMB       64
#define NCLS      128
#define N_SUPPORT 12800
#define N_QUERY   32768
#define N_ITEMS   (N_SUPPORT + N_QUERY)   // 45568
#define EPS_F     1e-8f

#define SUP_BLOCKS (N_SUPPORT / 8)   // 1600
#define QRY_BLOCKS (N_QUERY / 8)     // 4096

// ---------------------------------------------------------------------------
// DIAGNOSTIC ROUND: pool_all_k does its real pass (A) plus TWO discarded
// streaming passes (B, C) over item ranges rotated by N/3 and 2N/3.
// Purpose: force the kernel above the harness's ~240us fill dispatches so
// rocprof's top-5 shows OUR counters (hbm_gbps / VALUBusy / Occupancy), and
// make dur_us discriminate "harness floor ~230us" vs "streaming caps at
// ~2.6 TB/s". Numerics of the output are bit-identical to round 4 (pass A
// only feeds the result; B/C are kept live via asm sinks, never accumulated).
// REVERT B/C passes after reading the counters.
// ---------------------------------------------------------------------------

__global__ __launch_bounds__(256) void zero_ws_k(float* __restrict__ ws, int n) {
    int i = blockIdx.x * 256 + threadIdx.x;
    if (i < n) ws[i] = 0.0f;
}

__device__ inline const float4* item_base(const float* __restrict__ sup,
                                          const float* __restrict__ qry,
                                          int gi, int d4) {
    const float* s = (gi < N_SUPPORT)
        ? (sup + (size_t)gi * (SEQ_LEN * IN_DIM))
        : (qry + (size_t)(gi - N_SUPPORT) * (SEQ_LEN * IN_DIM));
    return reinterpret_cast<const float4*>(s) + d4;
}

__global__ __launch_bounds__(256) void pool_all_k(
    const float* __restrict__ support, const int* __restrict__ labels,
    const float* __restrict__ query,   const float* __restrict__ W,
    const float* __restrict__ b,
    float* __restrict__ classSum, float* __restrict__ classCount,
    float* __restrict__ qe)
{
    __shared__ float4 red[256];                 // 4 KB
    __shared__ float  pooled[8][IN_DIM];        // 1 KB
    __shared__ float  Wl[IN_DIM * EMB];         // 8 KB
    const int t = threadIdx.x;
    const bool isSup = blockIdx.x < SUP_BLOCKS;
    const int item0 = (isSup ? blockIdx.x : (blockIdx.x - SUP_BLOCKS)) * 8;

    if (!isSup) {
        #pragma unroll
        for (int j = 0; j < 8; ++j) Wl[t + j * 256] = W[t + j * 256];
    }

    const int combo = t & 63;
    const int li  = combo >> 3;
    const int d4  = combo & 7;
    const int rep = t >> 6;

    // ---- pass A: real data for this block's items (bit-identical to r4) ----
    const int gi = (isSup ? item0 : (N_SUPPORT + item0)) + li;
    const float4* baseA = item_base(support, query, gi, d4);
    float4 acc = make_float4(0.f, 0.f, 0.f, 0.f);
    #pragma unroll
    for (int i = 0; i < 25; ++i) {              // rows rep, rep+4, .., rep+96
        float4 v = baseA[(rep + 4 * i) * (IN_DIM / 4)];
        acc.x += v.x; acc.y += v.y; acc.z += v.z; acc.w += v.w;
    }

    // ---- pass B: rotated by N/3 (distant -> not L1-served), discarded ----
    {
        int giB = gi + 15189; if (giB >= N_ITEMS) giB -= N_ITEMS;
        const float4* baseB = item_base(support, query, giB, d4);
        float4 aB = make_float4(0.f, 0.f, 0.f, 0.f);
        #pragma unroll
        for (int i = 0; i < 25; ++i) {
            float4 v = baseB[(rep + 4 * i) * (IN_DIM / 4)];
            aB.x += v.x; aB.y += v.y; aB.z += v.z; aB.w += v.w;
        }
        asm volatile("" :: "v"(aB.x), "v"(aB.y), "v"(aB.z), "v"(aB.w));
    }
    // ---- pass C: rotated by 2N/3, discarded ----
    {
        int giC = gi + 30378; if (giC >= N_ITEMS) giC -= N_ITEMS;
        const float4* baseC = item_base(support, query, giC, d4);
        float4 aC = make_float4(0.f, 0.f, 0.f, 0.f);
        #pragma unroll
        for (int i = 0; i < 25; ++i) {
            float4 v = baseC[(rep + 4 * i) * (IN_DIM / 4)];
            aC.x += v.x; aC.y += v.y; aC.z += v.z; aC.w += v.w;
        }
        asm volatile("" :: "v"(aC.x), "v"(aC.y), "v"(aC.z), "v"(aC.w));
    }

    red[t] = acc;
    __syncthreads();
    if (t < 64) {
        float4 a = red[t], b2 = red[t + 64], c = red[t + 128], d = red[t + 192];
        const float s = 1.0f / (float)SEQ_LEN;
        pooled[li][d4 * 4 + 0] = (a.x + b2.x + c.x + d.x) * s;
        pooled[li][d4 * 4 + 1] = (a.y + b2.y + c.y + d.y) * s;
        pooled[li][d4 * 4 + 2] = (a.z + b2.z + c.z + d.z) * s;
        pooled[li][d4 * 4 + 3] = (a.w + b2.w + c.w + d.w) * s;
    }
    __syncthreads();

    if (isSup) {
        const int li2 = t >> 5;
        const int k   = t & 31;
        const int lab = labels[item0 + li2];
        atomicAdd(&classSum[lab * IN_DIM + k], pooled[li2][k]);
        if (k == 0) atomicAdd(&classCount[lab], 1.0f);
    } else {
        #pragma unroll
        for (int j = 0; j < 2; ++j) {
            const int idx = t + j * 256;
            const int q = idx >> 6;
            const int d = idx & 63;
            float a2 = b[d];
            #pragma unroll
            for (int k = 0; k < IN_DIM; ++k)
                a2 += pooled[q][k] * Wl[k * EMB + d];
            qe[(size_t)(item0 + q) * EMB + d] = a2;
        }
    }
}

// prototypes[c][d] = (classSum[c][:]/count[c]) @ W[:,d] + b[d]
__global__ __launch_bounds__(256) void proto_finalize_k(
    const float* __restrict__ classSum, const float* __restrict__ classCount,
    const float* __restrict__ W, const float* __restrict__ b,
    float* __restrict__ protoOut)
{
    const int idx = blockIdx.x * 256 + threadIdx.x;   // 0..8191
    const int c = idx >> 6;
    const int d = idx & 63;
    const float cnt = classCount[c];
    const float inv = (cnt > 0.f) ? (1.0f / cnt) : 0.f;
    float acc = b[d];
    #pragma unroll
    for (int k = 0; k < IN_DIM; ++k)
        acc += classSum[c * IN_DIM + k] * inv * W[k * EMB + d];
    protoOut[idx] = acc;
}

// 16 queries per block: squared distances vs 128 prototypes (LDS-staged).
__global__ __launch_bounds__(256) void distances_k(
    const float* __restrict__ qe, const float* __restrict__ proto,
    float* __restrict__ logits)
{
    __shared__ float pl[NCLS * (EMB + 1)];      // 33 KB, stride-65
    __shared__ float ql[16 * EMB];              // 4 KB
    const int t = threadIdx.x;
    const int q0 = blockIdx.x * 16;

    #pragma unroll
    for (int j = 0; j < 32; ++j) {
        const int i = t + j * 256;
        pl[(i >> 6) * (EMB + 1) + (i & 63)] = proto[i];
    }
    #pragma unroll
    for (int j = 0; j < 4; ++j) {
        const int i = t + j * 256;
        ql[i] = qe[(size_t)q0 * EMB + i];
    }
    __syncthreads();

    float* outB = logits + (size_t)q0 * NCLS;
    #pragma unroll
    for (int j = 0; j < 8; ++j) {
        const int idx = t + j * 256;
        const int q = idx >> 7;
        const int c = idx & 127;
        const float* qv = ql + q * EMB;
        const float* pv = pl + c * (EMB + 1);
        float s2 = 0.f;
        #pragma unroll
        for (int d = 0; d < EMB; ++d) {
            float df = qv[d] - pv[d];
            s2 += df * df;
        }
        outB[idx] = -(s2 + EPS_F);
    }
}

// ---------------- fallback: fused path (ws too small) -----------------------
__device__ inline float4 wave_pool_fb(const float* __restrict__ src, int item, int lane) {
    const int d4 = lane & 7;
    const int ph = lane >> 3;
    const float4* base = reinterpret_cast<const float4*>(src)
                       + (size_t)item * (SEQ_LEN * IN_DIM / 4) + d4;
    float4 acc = make_float4(0.f, 0.f, 0.f, 0.f);
    for (int r = ph; r < SEQ_LEN; r += 8) {
        float4 v = base[r * (IN_DIM / 4)];
        acc.x += v.x; acc.y += v.y; acc.z += v.z; acc.w += v.w;
    }
    #pragma unroll
    for (int m = 8; m <= 32; m <<= 1) {
        acc.x += __shfl_xor(acc.x, m);
        acc.y += __shfl_xor(acc.y, m);
        acc.z += __shfl_xor(acc.z, m);
        acc.w += __shfl_xor(acc.w, m);
    }
    return acc;
}

__global__ __launch_bounds__(256) void support_accum_fb_k(
    const float* __restrict__ support, const int* __restrict__ labels,
    float* __restrict__ classSum, float* __restrict__ classCount)
{
    const int t = threadIdx.x;
    const int wave = t >> 6, lane = t & 63;
    const int item = blockIdx.x * 4 + wave;
    float4 acc = wave_pool_fb(support, item, lane);
    const float s = 1.0f / (float)SEQ_LEN;
    const int lab = labels[item];
    if (lane < 8) {
        float* dst = classSum + lab * IN_DIM + lane * 4;
        atomicAdd(dst + 0, acc.x * s);
        atomicAdd(dst + 1, acc.y * s);
        atomicAdd(dst + 2, acc.z * s);
        atomicAdd(dst + 3, acc.w * s);
    }
    if (lane == 0) atomicAdd(&classCount[lab], 1.0f);
}

__global__ __launch_bounds__(256) void query_logits_fused_k(
    const float* __restrict__ query, const float* __restrict__ W,
    const float* __restrict__ b, const float* __restrict__ proto,
    float* __restrict__ logits)
{
    __shared__ float Wl[IN_DIM * EMB];
    __shared__ float pl[NCLS * (EMB + 1)];
    __shared__ float qel[4 * EMB];
    const int t = threadIdx.x;
    const int wave = t >> 6, lane = t & 63;
    const int q0 = blockIdx.x * 4;

    #pragma unroll
    for (int j = 0; j < 8; ++j) Wl[t + j * 256] = W[t + j * 256];
    #pragma unroll
    for (int j = 0; j < 32; ++j) {
        const int i = t + j * 256;
        pl[(i >> 6) * (EMB + 1) + (i & 63)] = proto[i];
    }
    float4 acc = wave_pool_fb(query, q0 + wave, lane);
    const float s = 1.0f / (float)SEQ_LEN;
    acc.x *= s; acc.y *= s; acc.z *= s; acc.w *= s;
    float a2 = b[lane];
    #pragma unroll
    for (int k4 = 0; k4 < 8; ++k4) {
        const float px = __shfl(acc.x, k4);
        const float py = __shfl(acc.y, k4);
        const float pz = __shfl(acc.z, k4);
        const float pw = __shfl(acc.w, k4);
        a2 += px * Wl[(k4 * 4 + 0) * EMB + lane];
        a2 += py * Wl[(k4 * 4 + 1) * EMB + lane];
        a2 += pz * Wl[(k4 * 4 + 2) * EMB + lane];
        a2 += pw * Wl[(k4 * 4 + 3) * EMB + lane];
    }
    qel[t] = a2;
    __syncthreads();
    float* outB = logits + (size_t)q0 * NCLS;
    #pragma unroll
    for (int j = 0; j < 2; ++j) {
        const int idx = t + j * 256;
        const int q = idx >> 7;
        const int c = idx & 127;
        const float* qv = qel + q * EMB;
        const float* pv = pl + c * (EMB + 1);
        float s2 = 0.f;
        #pragma unroll
        for (int d = 0; d < EMB; ++d) {
            float df = qv[d] - pv[d];
            s2 += df * df;
        }
        outB[idx] = -(s2 + EPS_F);
    }
}

extern "C" void kernel_launch(void* const* d_in, const int* in_sizes, int n_in,
                              void* d_out, int out_size, void* d_ws, size_t ws_size,
                              hipStream_t stream) {
    const float* support = (const float*)d_in[0];
    const int*   labels  = (const int*)d_in[1];
    const float* query   = (const float*)d_in[2];
    const float* W       = (const float*)d_in[3];
    const float* b       = (const float*)d_in[4];

    float* out      = (float*)d_out;
    float* logits   = out;                                   // (32768, 128)
    float* protoOut = out + (size_t)N_QUERY * NCLS;          // (128, 64) tail

    float* classSum   = (float*)d_ws;                        // 128*32
    float* classCount = classSum + NCLS * IN_DIM;            // 128
    float* qeWs       = classCount + NCLS;                   // 32768*64
    const int nZero = NCLS * IN_DIM + NCLS;                  // 4224
    const size_t wsNeeded = (size_t)(nZero + N_QUERY * EMB) * sizeof(float);

    zero_ws_k<<<(nZero + 255) / 256, 256, 0, stream>>>(classSum, nZero);

    if (ws_size >= wsNeeded) {
        pool_all_k<<<SUP_BLOCKS + QRY_BLOCKS, 256, 0, stream>>>(
            support, labels, query, W, b, classSum, classCount, qeWs);
        proto_finalize_k<<<(NCLS * EMB) / 256, 256, 0, stream>>>(classSum, classCount, W, b, protoOut);
        distances_k<<<N_QUERY / 16, 256, 0, stream>>>(qeWs, protoOut, logits);
    } else {
        support_accum_fb_k<<<N_SUPPORT / 4, 256, 0, stream>>>(support, labels, classSum, classCount);
        proto_finalize_k<<<(NCLS * EMB) / 256, 256, 0, stream>>>(classSum, classCount, W, b, protoOut);
        query_logits_fused_k<<<N_QUERY / 4, 256, 0, stream>>>(query, W, b, protoOut, logits);
    }
}

// Round 6
// 229.204 us; speedup vs baseline: 1.8286x; 1.8286x over previous
//
#include <hip/hip_runtime.h>

#define SEQ_LEN   100
#define IN_DIM    32
#define EMB       64
#define NCLS      128
#define N_SUPPORT 12800
#define N_QUERY   32768
#define EPS_F     1e-8f

#define SUP_BLOCKS (N_SUPPORT / 8)   // 1600
#define QRY_BLOCKS (N_QUERY / 8)     // 4096

// ---------------------------------------------------------------------------
// ws layout (floats):
//   [0, 4096)            classSum[128][32]
//   [4096, 4224)         classCount[128]
//   [4224, 4224+2097152) qe[32768][64]        (split path only)
// Prototypes live in d_out tail (proto_finalize writes, distances reads).
//
// NOTE (measurement floor, rounds 2-5): the harness's per-replay 1.638 GB
// fillBufferAligned (~235-254 us @ ~6.9 TB/s) runs inside the timed window;
// our full chain (~140-150 us: pool ~118 @ ~5 TB/s delivered, distances ~15,
// proto/zero ~5) hides beneath it. dur_us ~= max(fill, chain) ~= 230-245.
// Verified by a 3x-traffic diagnostic (round 5): window 419 us, pool_all at
// 2.5 TB/s HBM concurrent with the fill, VALUBusy 4%, occupancy 73%.
// ---------------------------------------------------------------------------

__global__ __launch_bounds__(256) void zero_ws_k(float* __restrict__ ws, int n) {
    int i = blockIdx.x * 256 + threadIdx.x;
    if (i < n) ws[i] = 0.0f;
}

// Unified pooling kernel: blocks [0,1600) support, [1600,5696) query.
// 8 items/block; combo-lane float4 loads, 25-deep compile-time row loop.
__global__ __launch_bounds__(256) void pool_all_k(
    const float* __restrict__ support, const int* __restrict__ labels,
    const float* __restrict__ query,   const float* __restrict__ W,
    const float* __restrict__ b,
    float* __restrict__ classSum, float* __restrict__ classCount,
    float* __restrict__ qe)
{
    __shared__ float4 red[256];                 // 4 KB
    __shared__ float  pooled[8][IN_DIM];        // 1 KB
    __shared__ float  Wl[IN_DIM * EMB];         // 8 KB
    const int t = threadIdx.x;
    const bool isSup = blockIdx.x < SUP_BLOCKS;
    const int item0 = (isSup ? blockIdx.x : (blockIdx.x - SUP_BLOCKS)) * 8;
    const float* src = isSup ? support : query;

    if (!isSup) {
        #pragma unroll
        for (int j = 0; j < 8; ++j) Wl[t + j * 256] = W[t + j * 256];
    }

    const int combo = t & 63;
    const int li  = combo >> 3;
    const int d4  = combo & 7;
    const int rep = t >> 6;

    const float4* base = reinterpret_cast<const float4*>(src)
                       + (size_t)(item0 + li) * (SEQ_LEN * IN_DIM / 4) + d4;
    float4 acc = make_float4(0.f, 0.f, 0.f, 0.f);
    #pragma unroll
    for (int i = 0; i < 25; ++i) {              // rows rep, rep+4, .., rep+96
        float4 v = base[(rep + 4 * i) * (IN_DIM / 4)];
        acc.x += v.x; acc.y += v.y; acc.z += v.z; acc.w += v.w;
    }
    red[t] = acc;
    __syncthreads();
    if (t < 64) {
        float4 a = red[t], b2 = red[t + 64], c = red[t + 128], d = red[t + 192];
        const float s = 1.0f / (float)SEQ_LEN;
        pooled[li][d4 * 4 + 0] = (a.x + b2.x + c.x + d.x) * s;
        pooled[li][d4 * 4 + 1] = (a.y + b2.y + c.y + d.y) * s;
        pooled[li][d4 * 4 + 2] = (a.z + b2.z + c.z + d.z) * s;
        pooled[li][d4 * 4 + 3] = (a.w + b2.w + c.w + d.w) * s;
    }
    __syncthreads();

    if (isSup) {
        // 8 items x 32 dims = 256 atomic adds, one per thread
        const int li2 = t >> 5;
        const int k   = t & 31;
        const int lab = labels[item0 + li2];
        atomicAdd(&classSum[lab * IN_DIM + k], pooled[li2][k]);
        if (k == 0) atomicAdd(&classCount[lab], 1.0f);
    } else {
        // projection: 8 q x 64 d = 512 outputs, 2 per thread; coalesced stores
        #pragma unroll
        for (int j = 0; j < 2; ++j) {
            const int idx = t + j * 256;
            const int q = idx >> 6;             // wave-uniform
            const int d = idx & 63;
            float a2 = b[d];
            #pragma unroll
            for (int k = 0; k < IN_DIM; ++k)
                a2 += pooled[q][k] * Wl[k * EMB + d];  // broadcast + 2-way (free)
            qe[(size_t)(item0 + q) * EMB + d] = a2;
        }
    }
}

// prototypes[c][d] = (classSum[c][:]/count[c]) @ W[:,d] + b[d]
__global__ __launch_bounds__(256) void proto_finalize_k(
    const float* __restrict__ classSum, const float* __restrict__ classCount,
    const float* __restrict__ W, const float* __restrict__ b,
    float* __restrict__ protoOut)
{
    const int idx = blockIdx.x * 256 + threadIdx.x;   // 0..8191
    const int c = idx >> 6;
    const int d = idx & 63;
    const float cnt = classCount[c];
    const float inv = (cnt > 0.f) ? (1.0f / cnt) : 0.f;
    float acc = b[d];
    #pragma unroll
    for (int k = 0; k < IN_DIM; ++k)
        acc += classSum[c * IN_DIM + k] * inv * W[k * EMB + d];
    protoOut[idx] = acc;
}

// 16 queries per block: squared distances vs 128 prototypes (LDS-staged).
__global__ __launch_bounds__(256) void distances_k(
    const float* __restrict__ qe, const float* __restrict__ proto,
    float* __restrict__ logits)
{
    __shared__ float pl[NCLS * (EMB + 1)];      // 33 KB, stride-65
    __shared__ float ql[16 * EMB];              // 4 KB
    const int t = threadIdx.x;
    const int q0 = blockIdx.x * 16;

    #pragma unroll
    for (int j = 0; j < 32; ++j) {
        const int i = t + j * 256;
        pl[(i >> 6) * (EMB + 1) + (i & 63)] = proto[i];
    }
    #pragma unroll
    for (int j = 0; j < 4; ++j) {
        const int i = t + j * 256;
        ql[i] = qe[(size_t)q0 * EMB + i];
    }
    __syncthreads();

    float* outB = logits + (size_t)q0 * NCLS;
    #pragma unroll
    for (int j = 0; j < 8; ++j) {
        const int idx = t + j * 256;
        const int q = idx >> 7;                 // uniform per wave
        const int c = idx & 127;                // lane-varying
        const float* qv = ql + q * EMB;         // broadcast
        const float* pv = pl + c * (EMB + 1);   // 2-way bank alias (free)
        float s2 = 0.f;
        #pragma unroll
        for (int d = 0; d < EMB; ++d) {
            float df = qv[d] - pv[d];
            s2 += df * df;
        }
        outB[idx] = -(s2 + EPS_F);
    }
}

// ---------------- fallback: fused path (ws too small) -----------------------
__device__ inline float4 wave_pool_fb(const float* __restrict__ src, int item, int lane) {
    const int d4 = lane & 7;
    const int ph = lane >> 3;
    const float4* base = reinterpret_cast<const float4*>(src)
                       + (size_t)item * (SEQ_LEN * IN_DIM / 4) + d4;
    float4 acc = make_float4(0.f, 0.f, 0.f, 0.f);
    for (int r = ph; r < SEQ_LEN; r += 8) {
        float4 v = base[r * (IN_DIM / 4)];
        acc.x += v.x; acc.y += v.y; acc.z += v.z; acc.w += v.w;
    }
    #pragma unroll
    for (int m = 8; m <= 32; m <<= 1) {
        acc.x += __shfl_xor(acc.x, m);
        acc.y += __shfl_xor(acc.y, m);
        acc.z += __shfl_xor(acc.z, m);
        acc.w += __shfl_xor(acc.w, m);
    }
    return acc;
}

__global__ __launch_bounds__(256) void support_accum_fb_k(
    const float* __restrict__ support, const int* __restrict__ labels,
    float* __restrict__ classSum, float* __restrict__ classCount)
{
    const int t = threadIdx.x;
    const int wave = t >> 6, lane = t & 63;
    const int item = blockIdx.x * 4 + wave;
    float4 acc = wave_pool_fb(support, item, lane);
    const float s = 1.0f / (float)SEQ_LEN;
    const int lab = labels[item];
    if (lane < 8) {
        float* dst = classSum + lab * IN_DIM + lane * 4;
        atomicAdd(dst + 0, acc.x * s);
        atomicAdd(dst + 1, acc.y * s);
        atomicAdd(dst + 2, acc.z * s);
        atomicAdd(dst + 3, acc.w * s);
    }
    if (lane == 0) atomicAdd(&classCount[lab], 1.0f);
}

__global__ __launch_bounds__(256) void query_logits_fused_k(
    const float* __restrict__ query, const float* __restrict__ W,
    const float* __restrict__ b, const float* __restrict__ proto,
    float* __restrict__ logits)
{
    __shared__ float Wl[IN_DIM * EMB];
    __shared__ float pl[NCLS * (EMB + 1)];
    __shared__ float qel[4 * EMB];
    const int t = threadIdx.x;
    const int wave = t >> 6, lane = t & 63;
    const int q0 = blockIdx.x * 4;

    #pragma unroll
    for (int j = 0; j < 8; ++j) Wl[t + j * 256] = W[t + j * 256];
    #pragma unroll
    for (int j = 0; j < 32; ++j) {
        const int i = t + j * 256;
        pl[(i >> 6) * (EMB + 1) + (i & 63)] = proto[i];
    }
    float4 acc = wave_pool_fb(query, q0 + wave, lane);
    const float s = 1.0f / (float)SEQ_LEN;
    acc.x *= s; acc.y *= s; acc.z *= s; acc.w *= s;
    float a2 = b[lane];
    #pragma unroll
    for (int k4 = 0; k4 < 8; ++k4) {
        const float px = __shfl(acc.x, k4);
        const float py = __shfl(acc.y, k4);
        const float pz = __shfl(acc.z, k4);
        const float pw = __shfl(acc.w, k4);
        a2 += px * Wl[(k4 * 4 + 0) * EMB + lane];
        a2 += py * Wl[(k4 * 4 + 1) * EMB + lane];
        a2 += pz * Wl[(k4 * 4 + 2) * EMB + lane];
        a2 += pw * Wl[(k4 * 4 + 3) * EMB + lane];
    }
    qel[t] = a2;
    __syncthreads();
    float* outB = logits + (size_t)q0 * NCLS;
    #pragma unroll
    for (int j = 0; j < 2; ++j) {
        const int idx = t + j * 256;
        const int q = idx >> 7;
        const int c = idx & 127;
        const float* qv = qel + q * EMB;
        const float* pv = pl + c * (EMB + 1);
        float s2 = 0.f;
        #pragma unroll
        for (int d = 0; d < EMB; ++d) {
            float df = qv[d] - pv[d];
            s2 += df * df;
        }
        outB[idx] = -(s2 + EPS_F);
    }
}

extern "C" void kernel_launch(void* const* d_in, const int* in_sizes, int n_in,
                              void* d_out, int out_size, void* d_ws, size_t ws_size,
                              hipStream_t stream) {
    const float* support = (const float*)d_in[0];
    const int*   labels  = (const int*)d_in[1];
    const float* query   = (const float*)d_in[2];
    const float* W       = (const float*)d_in[3];
    const float* b       = (const float*)d_in[4];

    float* out      = (float*)d_out;
    float* logits   = out;                                   // (32768, 128)
    float* protoOut = out + (size_t)N_QUERY * NCLS;          // (128, 64) tail

    float* classSum   = (float*)d_ws;                        // 128*32
    float* classCount = classSum + NCLS * IN_DIM;            // 128
    float* qeWs       = classCount + NCLS;                   // 32768*64
    const int nZero = NCLS * IN_DIM + NCLS;                  // 4224
    const size_t wsNeeded = (size_t)(nZero + N_QUERY * EMB) * sizeof(float);

    zero_ws_k<<<(nZero + 255) / 256, 256, 0, stream>>>(classSum, nZero);

    if (ws_size >= wsNeeded) {
        pool_all_k<<<SUP_BLOCKS + QRY_BLOCKS, 256, 0, stream>>>(
            support, labels, query, W, b, classSum, classCount, qeWs);
        proto_finalize_k<<<(NCLS * EMB) / 256, 256, 0, stream>>>(classSum, classCount, W, b, protoOut);
        distances_k<<<N_QUERY / 16, 256, 0, stream>>>(qeWs, protoOut, logits);
    } else {
        support_accum_fb_k<<<N_SUPPORT / 4, 256, 0, stream>>>(support, labels, classSum, classCount);
        proto_finalize_k<<<(NCLS * EMB) / 256, 256, 0, stream>>>(classSum, classCount, W, b, protoOut);
        query_logits_fused_k<<<N_QUERY / 4, 256, 0, stream>>>(query, W, b, protoOut, logits);
    }
}